// Round 9
// baseline (307.669 us; speedup 1.0000x reference)
//
#include <hip/hip_runtime.h>

#define B_   8
#define S_   2048
#define IN_  96
#define H_   256
#define NROW (B_ * S_)          // 16384 rows

typedef float    f32x4 __attribute__((ext_vector_type(4)));
typedef _Float16 f16x8 __attribute__((ext_vector_type(8)));   // 8 fp16 in 4 VGPRs

__device__ __forceinline__ unsigned short f2h(float x) {
    return __builtin_bit_cast(unsigned short, (_Float16)x);
}
__device__ __forceinline__ float h2f(unsigned short x) {
    return (float)__builtin_bit_cast(_Float16, x);
}
// non-temporal 16B load (mask is a read-once 134MB stream — keep it from
// evicting K/V out of the 4MB per-XCD L2)
__device__ __forceinline__ int4 nt_load_int4(const int* p) {
    long long v0 = __builtin_nontemporal_load((const long long*)p);
    long long v1 = __builtin_nontemporal_load(((const long long*)p) + 1);
    int4 r;
    r.x = (int)(v0 & 0xffffffffLL); r.y = (int)(v0 >> 32);
    r.z = (int)(v1 & 0xffffffffLL); r.w = (int)(v1 >> 32);
    return r;
}

// ---------------------------------------------------------------------------
// Kernel 0: convert W[96][256] fp32 -> wt[256][96] fp16 (transposed), x3 proj.
// ---------------------------------------------------------------------------
__global__ __launch_bounds__(256) void wconv_kernel(
    const float* __restrict__ Wq, const float* __restrict__ Wk,
    const float* __restrict__ Wv, unsigned short* __restrict__ wt)
{
    const int p  = blockIdx.x >> 3;
    const int h0 = (blockIdx.x & 7) * 32;
    const float* W = (p == 0) ? Wq : (p == 1) ? Wk : Wv;
    unsigned short* dst = wt + (size_t)p * H_ * IN_ + (size_t)h0 * IN_;

    __shared__ unsigned short lds[32][100];
    const int t = threadIdx.x;
    #pragma unroll
    for (int i = 0; i < 12; ++i) {
        int idx = i * 256 + t;
        int f = idx >> 5;
        int hl = idx & 31;
        lds[hl][f] = f2h(W[f * H_ + h0 + hl]);
    }
    __syncthreads();
    #pragma unroll
    for (int j = 0; j < 6; ++j) {
        int e = (j * 256 + t) * 2;
        int hl = e / IN_, f = e % IN_;
        unsigned int pk = (unsigned int)lds[hl][f] |
                          ((unsigned int)lds[hl][f + 1] << 16);
        ((unsigned int*)dst)[j * 256 + t] = pk;
    }
}

// ---------------------------------------------------------------------------
// Kernel 1: QKV projection via fp16 MFMA, writing FRAGMENT-PACKED outputs
// (unchanged from round 8):
//   pq/pk[t(16-row tile)][s(32-h grp)][lane][8]   (B-/A-frag order, QK^T)
//   pv[bc(64-key chunk)][cid = w*8+ht*2+s2][lane][8]  (B-frag order, PV)
// ---------------------------------------------------------------------------
__global__ __launch_bounds__(256) void proj_kernel3(
    const float* __restrict__ query, const float* __restrict__ key,
    const float* __restrict__ value, const unsigned short* __restrict__ wt,
    const float* __restrict__ bq, const float* __restrict__ bk,
    const float* __restrict__ bv,
    unsigned short* __restrict__ pq, unsigned short* __restrict__ pk,
    unsigned short* __restrict__ pv)
{
    __shared__ unsigned short Xs[3][16][104];     // [p][r][f], pitch 104

    const int t    = threadIdx.x;
    const int lane = t & 63;
    const int wave = t >> 6;
    const int col  = lane & 15;
    const int quad = lane >> 4;
    const int bi   = blockIdx.x;                  // global 16-row tile id
    const int s0   = bi * 16;                     // flat row (b*S + sl)
    const int b    = s0 >> 11;
    const int sl   = s0 & (S_ - 1);

    const float* srcs[3] = { query + (size_t)s0 * IN_,
                             key   + (size_t)s0 * IN_,
                             value + (size_t)s0 * IN_ };
    #pragma unroll
    for (int p = 0; p < 3; ++p) {
        #pragma unroll
        for (int i = 0; i < 2; ++i) {
            int idx = i * 256 + t;                // float4 index, 384 total
            if (idx < 384) {
                f32x4 x = *(const f32x4*)(srcs[p] + idx * 4);
                int r = idx / 24;
                int f = (idx - r * 24) * 4;
                unsigned long long pkk =
                    (unsigned long long)f2h(x[0])
                  | ((unsigned long long)f2h(x[1]) << 16)
                  | ((unsigned long long)f2h(x[2]) << 32)
                  | ((unsigned long long)f2h(x[3]) << 48);
                *(unsigned long long*)&Xs[p][r][f] = pkk;
            }
        }
    }
    __syncthreads();

    const int hc = wave;
    #pragma unroll
    for (int p = 0; p < 3; ++p) {
        const unsigned short* wbase = wt + (size_t)p * H_ * IN_;
        f16x8 wfr[4][3];
        #pragma unroll
        for (int ht = 0; ht < 4; ++ht)
            #pragma unroll
            for (int kc = 0; kc < 3; ++kc)
                wfr[ht][kc] = *(const f16x8*)(wbase
                    + (size_t)(hc * 64 + ht * 16 + col) * IN_ + kc * 32 + quad * 8);
        f16x8 xfr[3];
        #pragma unroll
        for (int kc = 0; kc < 3; ++kc)
            xfr[kc] = *(const f16x8*)&Xs[p][col][kc * 32 + quad * 8];

        f32x4 acc[4];
        #pragma unroll
        for (int ht = 0; ht < 4; ++ht) acc[ht] = (f32x4)(0.0f);
        #pragma unroll
        for (int kc = 0; kc < 3; ++kc)
            #pragma unroll
            for (int ht = 0; ht < 4; ++ht)
                acc[ht] = (p < 2)
                    ? __builtin_amdgcn_mfma_f32_16x16x32_f16(xfr[kc], wfr[ht][kc], acc[ht], 0, 0, 0)
                    : __builtin_amdgcn_mfma_f32_16x16x32_f16(wfr[ht][kc], xfr[kc], acc[ht], 0, 0, 0);

        if (p < 2) {
            unsigned short* dst  = (p == 0) ? pq : pk;
            const float*    bias = (p == 0) ? bq : bk;
            #pragma unroll
            for (int ht = 0; ht < 4; ++ht) {
                float bh = bias[hc * 64 + ht * 16 + col];
                const int s    = hc * 2 + (ht >> 1);
                const int lq   = ((ht & 1) * 2 + (col >> 3)) * 16;
                const int j    = col & 7;
                #pragma unroll
                for (int r = 0; r < 4; ++r)
                    dst[(size_t)(((bi * 8 + s) * 64 + lq + quad * 4 + r)) * 8 + j]
                        = f2h(acc[ht][r] + bh);
            }
        } else {
            const int kl  = (sl & 63) + col;      // key within 64-chunk
            const int c   = sl >> 6;              // chunk within batch
            const int s2  = kl >> 5;
            const int qv  = (kl >> 3) & 3;
            const int jj  = col & 7;
            #pragma unroll
            for (int ht = 0; ht < 4; ++ht) {
                f32x4 b4 = *(const f32x4*)(bv + hc * 64 + ht * 16 + quad * 4);
                #pragma unroll
                for (int r = 0; r < 4; ++r)
                    pv[(size_t)(((b * 32 + c) * 32 + hc * 8 + ht * 2 + s2) * 64
                                + qv * 16 + quad * 4 + r) * 8 + jj]
                        = f2h(acc[ht][r] + b4[r]);
            }
        }
    }
}

// ---------------------------------------------------------------------------
// Kernel 2: flash attention, KEY-SPLIT partial version. Fixed-max softmax
// makes partials exactly additive, so grid = 8 batch x 64 strip x 2 key-half
// = 1024 blocks (4/CU — round 8 was grid-limited to 2/CU at 512 blocks).
// Each block: 32 q rows x 1024 keys = 16 chunks of 64 keys; same inner loop
// as round 8 (K dbuf, V early-issue, 1 barrier/chunk, pitch-68 P). Writes
// fp16 partial O and fp32 partial l; merge+LN kernel combines the 2 halves.
// Mask loads are NON-TEMPORAL (read-once stream was evicting K/V from L2).
// ---------------------------------------------------------------------------
__global__ __launch_bounds__(256, 2) void attn_kernel(
    const unsigned short* __restrict__ pq, const unsigned short* __restrict__ pk,
    const unsigned short* __restrict__ pv, const int* __restrict__ mask,
    unsigned short* __restrict__ Opart, float* __restrict__ lpart)
{
    __shared__ unsigned short P[2][32][68];       // [buf][q(2 strips)][k], pitch 68
    __shared__ float lsum[4][32];

    const int tid  = threadIdx.x;
    const int wave = tid >> 6;
    const int lane = tid & 63;
    const int col  = lane & 15;
    const int quad = lane >> 4;

    const int b     = blockIdx.x & 7;             // batch == XCD (L2 locality)
    const int strip = (blockIdx.x >> 3) & 63;     // 0..63 (32 rows each)
    const int kh    = blockIdx.x >> 9;            // key half: 0 or 1
    const int q0    = strip << 5;

    // Q B-fragments for both 16-row strips: 16 coalesced 1KB loads, resident.
    f16x8 qf[2][8];
    #pragma unroll
    for (int st = 0; st < 2; ++st) {
        const unsigned short* qb = pq + (size_t)(b * 128 + strip * 2 + st) * 4096
                                      + lane * 8;
        #pragma unroll
        for (int s = 0; s < 8; ++s) qf[st][s] = *(const f16x8*)(qb + s * 512);
    }

    f32x4 O[2][4];                                // [strip][ht] 64-h slice
    #pragma unroll
    for (int st = 0; st < 2; ++st)
        #pragma unroll
        for (int ht = 0; ht < 4; ++ht) O[st][ht] = (f32x4)(0.0f);
    float l0 = 0.0f, l1 = 0.0f;

    const unsigned short* pkb = pk + (size_t)(b * 128) * 4096 + lane * 8;
    const unsigned short* pvb = pv + (size_t)(b * 32) * 32 * 512
                                   + (size_t)wave * 8 * 512 + lane * 8;
    const int* mb0 = mask + (size_t)(b * S_ + q0 + col) * S_ + kh * 1024
                   + wave * 16 + quad * 4;
    const int* mb1 = mb0 + 16 * S_;

    // K double buffer: prologue load for chunk 0 (key tile kh*64 + wave)
    f16x8 kf[2][8];
    #pragma unroll
    for (int s = 0; s < 8; ++s)
        kf[0][s] = *(const f16x8*)(pkb + (size_t)(kh * 64 + wave) * 4096 + s * 512);

    int4 mc0 = nt_load_int4(mb0);
    int4 mc1 = nt_load_int4(mb1);

    #pragma unroll 2
    for (int c = 0; c < 16; ++c) {
        const int pb = c & 1;
        const int cn = (c < 15) ? c + 1 : c;      // clamped prefetch index
        const int gc = kh * 16 + c;               // global 64-key chunk

        // ---- V loads for this chunk (needed right after barrier) ----
        const unsigned short* vb = pvb + (size_t)gc * 32 * 512;
        f16x8 vf[4][2];
        #pragma unroll
        for (int ht = 0; ht < 4; ++ht)
            #pragma unroll
            for (int s2 = 0; s2 < 2; ++s2)
                vf[ht][s2] = *(const f16x8*)(vb + (size_t)(ht * 2 + s2) * 512);

        // ---- mask prefetch for next chunk (non-temporal) ----
        int4 mn0 = nt_load_int4(mb0 + cn * 64);
        int4 mn1 = nt_load_int4(mb1 + cn * 64);

        // ---- S^T = K·Q^T for both strips (key tile kh*64 + c*4 + wave) ----
        f32x4 St0 = (f32x4)(0.0f), St1 = (f32x4)(0.0f);
        #pragma unroll
        for (int s = 0; s < 8; ++s) {
            St0 = __builtin_amdgcn_mfma_f32_16x16x32_f16(kf[pb][s], qf[0][s], St0, 0, 0, 0);
            St1 = __builtin_amdgcn_mfma_f32_16x16x32_f16(kf[pb][s], qf[1][s], St1, 0, 0, 0);
        }

        // ---- K prefetch for next chunk ----
        {
            const unsigned short* kb = pkb + (size_t)(kh * 64 + cn * 4 + wave) * 4096;
            #pragma unroll
            for (int s = 0; s < 8; ++s)
                kf[pb ^ 1][s] = *(const f16x8*)(kb + s * 512);
        }

        // ---- fixed-max softmax: p = exp(s/16 - 6), masked -> 0 ----
        {
            int mi[4] = { mc0.x, mc0.y, mc0.z, mc0.w };
            unsigned long long pk64 = 0;
            #pragma unroll
            for (int r = 0; r < 4; ++r) {
                float p = (mi[r] == 0) ? 0.0f : __expf(St0[r] * 0.0625f - 6.0f);
                _Float16 ph = (_Float16)p;
                l0 += (float)ph;                  // denom from quantized p
                pk64 |= (unsigned long long)__builtin_bit_cast(unsigned short, ph)
                        << (16 * r);
            }
            *(unsigned long long*)&P[pb][col][wave * 16 + quad * 4] = pk64;
        }
        {
            int mi[4] = { mc1.x, mc1.y, mc1.z, mc1.w };
            unsigned long long pk64 = 0;
            #pragma unroll
            for (int r = 0; r < 4; ++r) {
                float p = (mi[r] == 0) ? 0.0f : __expf(St1[r] * 0.0625f - 6.0f);
                _Float16 ph = (_Float16)p;
                l1 += (float)ph;
                pk64 |= (unsigned long long)__builtin_bit_cast(unsigned short, ph)
                        << (16 * r);
            }
            *(unsigned long long*)&P[pb][16 + col][wave * 16 + quad * 4] = pk64;
        }
        mc0 = mn0; mc1 = mn1;

        __syncthreads();                          // P visible (1 barrier/chunk)

        // ---- O += P · V (64-key chunk, this wave's 64-h slice, 2 strips) ----
        #pragma unroll
        for (int st = 0; st < 2; ++st) {
            #pragma unroll
            for (int s2 = 0; s2 < 2; ++s2) {
                union { unsigned long long u[2]; f16x8 v; } pu;
                const unsigned short* pr = &P[pb][st * 16 + col][s2 * 32 + quad * 8];
                pu.u[0] = *(const unsigned long long*)pr;
                pu.u[1] = *(const unsigned long long*)(pr + 4);
                f16x8 pf = pu.v;
                #pragma unroll
                for (int ht = 0; ht < 4; ++ht)
                    O[st][ht] = __builtin_amdgcn_mfma_f32_16x16x32_f16(pf, vf[ht][s2], O[st][ht], 0, 0, 0);
            }
        }
    }

    // ---- reduce l per strip: quads via shfl, waves via LDS ----
    l0 += __shfl_xor(l0, 16); l0 += __shfl_xor(l0, 32);
    l1 += __shfl_xor(l1, 16); l1 += __shfl_xor(l1, 32);
    if (lane < 16) { lsum[wave][lane] = l0; lsum[wave][16 + lane] = l1; }
    __syncthreads();

    if (wave == 0 && lane < 16) {
        #pragma unroll
        for (int st = 0; st < 2; ++st) {
            float lt = lsum[0][st * 16 + lane] + lsum[1][st * 16 + lane]
                     + lsum[2][st * 16 + lane] + lsum[3][st * 16 + lane];
            lpart[(size_t)kh * NROW + b * S_ + q0 + st * 16 + lane] = lt;
        }
    }

    // ---- store fp16 partial O straight from registers (no epilogue LDS) ----
    // lane(col,quad) reg r of O[st][ht]: row = q0+st*16+quad*4+r,
    // h = wave*64+ht*16+col  -> 16-lane 32B runs x 4 rows per instr.
    unsigned short* ob = Opart + (size_t)kh * NROW * H_ + (size_t)(b * S_) * H_;
    #pragma unroll
    for (int st = 0; st < 2; ++st)
        #pragma unroll
        for (int ht = 0; ht < 4; ++ht)
            #pragma unroll
            for (int r = 0; r < 4; ++r)
                ob[(size_t)(q0 + st * 16 + quad * 4 + r) * H_
                   + wave * 64 + ht * 16 + col] = f2h(O[st][ht][r]);
}

// ---------------------------------------------------------------------------
// Kernel 3: merge the 2 key-half partials + normalize + LayerNorm.
// 1024 blocks x 256 thr; block = 16 rows. Memory-bound (~50 MB total).
// ---------------------------------------------------------------------------
__global__ __launch_bounds__(256) void merge_ln_kernel(
    const unsigned short* __restrict__ Opart, const float* __restrict__ lpart,
    const float* __restrict__ gamma, const float* __restrict__ beta,
    float* __restrict__ out)
{
    const int R0 = blockIdx.x * 16;
    const int q  = threadIdx.x >> 4;              // row R0+q
    const int i  = threadIdx.x & 15;

    const size_t row = (size_t)(R0 + q);
    float linv = 1.0f / (lpart[row] + lpart[NROW + row]);

    const unsigned short* o0 = Opart + row * H_;
    const unsigned short* o1 = o0 + (size_t)NROW * H_;

    float vals[16];
    float sum = 0.0f;
    #pragma unroll
    for (int j = 0; j < 16; ++j) {
        int h = j * 16 + i;
        vals[j] = (h2f(o0[h]) + h2f(o1[h])) * linv;
        sum += vals[j];
    }
    sum += __shfl_xor(sum, 1);
    sum += __shfl_xor(sum, 2);
    sum += __shfl_xor(sum, 4);
    sum += __shfl_xor(sum, 8);
    float mu = sum * (1.0f / H_);
    float sq = 0.0f;
    #pragma unroll
    for (int j = 0; j < 16; ++j) {
        float d = vals[j] - mu;
        sq += d * d;
    }
    sq += __shfl_xor(sq, 1);
    sq += __shfl_xor(sq, 2);
    sq += __shfl_xor(sq, 4);
    sq += __shfl_xor(sq, 8);
    float rstd = rsqrtf(sq * (1.0f / H_) + 1e-6f);

    float* orow = out + row * H_;
    #pragma unroll
    for (int j = 0; j < 16; ++j) {
        int h = j * 16 + i;
        orow[h] = (vals[j] - mu) * rstd * gamma[h] + beta[h];
    }
}

// ---------------------------------------------------------------------------
extern "C" void kernel_launch(void* const* d_in, const int* in_sizes, int n_in,
                              void* d_out, int out_size, void* d_ws, size_t ws_size,
                              hipStream_t stream)
{
    const float* query = (const float*)d_in[0];
    const float* key   = (const float*)d_in[1];
    const float* value = (const float*)d_in[2];
    const int*   mask  = (const int*)d_in[3];
    const float* Wq = (const float*)d_in[4];
    const float* bq = (const float*)d_in[5];
    const float* Wk = (const float*)d_in[6];
    const float* bk = (const float*)d_in[7];
    const float* Wv = (const float*)d_in[8];
    const float* bv = (const float*)d_in[9];
    const float* gamma = (const float*)d_in[10];
    const float* beta  = (const float*)d_in[11];
    float* out = (float*)d_out;

    const size_t NQK = (size_t)B_ * S_ * H_;             // 4.19M elem each
    unsigned short* pq = (unsigned short*)d_ws;          // frag-packed Q (fp16)
    unsigned short* pk = pq + NQK;                       // frag-packed K (fp16)
    unsigned short* pv = pk + NQK;                       // frag-packed V (fp16)
    unsigned short* wt = pv + NQK;                       // [3][256][96] fp16
    unsigned short* Op = wt + (size_t)3 * H_ * IN_;      // [2][NROW][256] fp16
    float*          lp = (float*)(Op + (size_t)2 * NROW * H_);  // [2][NROW] fp32

    wconv_kernel<<<24, 256, 0, stream>>>(Wq, Wk, Wv, wt);
    proj_kernel3<<<B_ * S_ / 16, 256, 0, stream>>>(query, key, value, wt,
                                                   bq, bk, bv, pq, pk, pv);
    attn_kernel<<<B_ * S_ / 32 * 2, 256, 0, stream>>>(pq, pk, pv, mask, Op, lp);
    merge_ln_kernel<<<NROW / 16, 256, 0, stream>>>(Op, lp, gamma, beta, out);
}

// Round 10
// 303.176 us; speedup vs baseline: 1.0148x; 1.0148x over previous
//
#include <hip/hip_runtime.h>

#define B_   8
#define S_   2048
#define IN_  96
#define H_   256
#define NROW (B_ * S_)          // 16384 rows

typedef float    f32x4 __attribute__((ext_vector_type(4)));
typedef _Float16 f16x8 __attribute__((ext_vector_type(8)));   // 8 fp16 in 4 VGPRs

__device__ __forceinline__ unsigned short f2h(float x) {
    return __builtin_bit_cast(unsigned short, (_Float16)x);
}
__device__ __forceinline__ float h2f(unsigned short x) {
    return (float)__builtin_bit_cast(_Float16, x);
}
// LDS-only barrier: __syncthreads() emits s_waitcnt vmcnt(0) lgkmcnt(0) +
// s_barrier — the vmcnt(0) DRAINS every in-flight global prefetch at every
// chunk (the round-9 stall). P-visibility only needs lgkmcnt(0); vmem
// consumers get their own partial vmcnt(N) waits at first use.
__device__ __forceinline__ void lds_barrier() {
    asm volatile("s_waitcnt lgkmcnt(0)\n\ts_barrier" ::: "memory");
}
// non-temporal 16B load (mask is a read-once 134MB stream)
__device__ __forceinline__ int4 nt_load_int4(const int* p) {
    long long v0 = __builtin_nontemporal_load((const long long*)p);
    long long v1 = __builtin_nontemporal_load(((const long long*)p) + 1);
    int4 r;
    r.x = (int)(v0 & 0xffffffffLL); r.y = (int)(v0 >> 32);
    r.z = (int)(v1 & 0xffffffffLL); r.w = (int)(v1 >> 32);
    return r;
}

// ---------------------------------------------------------------------------
// Kernel 0: convert W[96][256] fp32 -> wt[256][96] fp16 (transposed), x3 proj.
// ---------------------------------------------------------------------------
__global__ __launch_bounds__(256) void wconv_kernel(
    const float* __restrict__ Wq, const float* __restrict__ Wk,
    const float* __restrict__ Wv, unsigned short* __restrict__ wt)
{
    const int p  = blockIdx.x >> 3;
    const int h0 = (blockIdx.x & 7) * 32;
    const float* W = (p == 0) ? Wq : (p == 1) ? Wk : Wv;
    unsigned short* dst = wt + (size_t)p * H_ * IN_ + (size_t)h0 * IN_;

    __shared__ unsigned short lds[32][100];
    const int t = threadIdx.x;
    #pragma unroll
    for (int i = 0; i < 12; ++i) {
        int idx = i * 256 + t;
        int f = idx >> 5;
        int hl = idx & 31;
        lds[hl][f] = f2h(W[f * H_ + h0 + hl]);
    }
    __syncthreads();
    #pragma unroll
    for (int j = 0; j < 6; ++j) {
        int e = (j * 256 + t) * 2;
        int hl = e / IN_, f = e % IN_;
        unsigned int pk = (unsigned int)lds[hl][f] |
                          ((unsigned int)lds[hl][f + 1] << 16);
        ((unsigned int*)dst)[j * 256 + t] = pk;
    }
}

// ---------------------------------------------------------------------------
// Kernel 1: QKV projection via fp16 MFMA, writing FRAGMENT-PACKED outputs
// (unchanged from round 8/9):
//   pq/pk[t(16-row tile)][s(32-h grp)][lane][8]   (B-/A-frag order, QK^T)
//   pv[bc(64-key chunk)][cid = w*8+ht*2+s2][lane][8]  (B-frag order, PV)
// ---------------------------------------------------------------------------
__global__ __launch_bounds__(256) void proj_kernel3(
    const float* __restrict__ query, const float* __restrict__ key,
    const float* __restrict__ value, const unsigned short* __restrict__ wt,
    const float* __restrict__ bq, const float* __restrict__ bk,
    const float* __restrict__ bv,
    unsigned short* __restrict__ pq, unsigned short* __restrict__ pk,
    unsigned short* __restrict__ pv)
{
    __shared__ unsigned short Xs[3][16][104];     // [p][r][f], pitch 104

    const int t    = threadIdx.x;
    const int lane = t & 63;
    const int wave = t >> 6;
    const int col  = lane & 15;
    const int quad = lane >> 4;
    const int bi   = blockIdx.x;                  // global 16-row tile id
    const int s0   = bi * 16;                     // flat row (b*S + sl)
    const int b    = s0 >> 11;
    const int sl   = s0 & (S_ - 1);

    const float* srcs[3] = { query + (size_t)s0 * IN_,
                             key   + (size_t)s0 * IN_,
                             value + (size_t)s0 * IN_ };
    #pragma unroll
    for (int p = 0; p < 3; ++p) {
        #pragma unroll
        for (int i = 0; i < 2; ++i) {
            int idx = i * 256 + t;                // float4 index, 384 total
            if (idx < 384) {
                f32x4 x = *(const f32x4*)(srcs[p] + idx * 4);
                int r = idx / 24;
                int f = (idx - r * 24) * 4;
                unsigned long long pkk =
                    (unsigned long long)f2h(x[0])
                  | ((unsigned long long)f2h(x[1]) << 16)
                  | ((unsigned long long)f2h(x[2]) << 32)
                  | ((unsigned long long)f2h(x[3]) << 48);
                *(unsigned long long*)&Xs[p][r][f] = pkk;
            }
        }
    }
    __syncthreads();

    const int hc = wave;
    #pragma unroll
    for (int p = 0; p < 3; ++p) {
        const unsigned short* wbase = wt + (size_t)p * H_ * IN_;
        f16x8 wfr[4][3];
        #pragma unroll
        for (int ht = 0; ht < 4; ++ht)
            #pragma unroll
            for (int kc = 0; kc < 3; ++kc)
                wfr[ht][kc] = *(const f16x8*)(wbase
                    + (size_t)(hc * 64 + ht * 16 + col) * IN_ + kc * 32 + quad * 8);
        f16x8 xfr[3];
        #pragma unroll
        for (int kc = 0; kc < 3; ++kc)
            xfr[kc] = *(const f16x8*)&Xs[p][col][kc * 32 + quad * 8];

        f32x4 acc[4];
        #pragma unroll
        for (int ht = 0; ht < 4; ++ht) acc[ht] = (f32x4)(0.0f);
        #pragma unroll
        for (int kc = 0; kc < 3; ++kc)
            #pragma unroll
            for (int ht = 0; ht < 4; ++ht)
                acc[ht] = (p < 2)
                    ? __builtin_amdgcn_mfma_f32_16x16x32_f16(xfr[kc], wfr[ht][kc], acc[ht], 0, 0, 0)
                    : __builtin_amdgcn_mfma_f32_16x16x32_f16(wfr[ht][kc], xfr[kc], acc[ht], 0, 0, 0);

        if (p < 2) {
            unsigned short* dst  = (p == 0) ? pq : pk;
            const float*    bias = (p == 0) ? bq : bk;
            #pragma unroll
            for (int ht = 0; ht < 4; ++ht) {
                float bh = bias[hc * 64 + ht * 16 + col];
                const int s    = hc * 2 + (ht >> 1);
                const int lq   = ((ht & 1) * 2 + (col >> 3)) * 16;
                const int j    = col & 7;
                #pragma unroll
                for (int r = 0; r < 4; ++r)
                    dst[(size_t)(((bi * 8 + s) * 64 + lq + quad * 4 + r)) * 8 + j]
                        = f2h(acc[ht][r] + bh);
            }
        } else {
            const int kl  = (sl & 63) + col;      // key within 64-chunk
            const int c   = sl >> 6;              // chunk within batch
            const int s2  = kl >> 5;
            const int qv  = (kl >> 3) & 3;
            const int jj  = col & 7;
            #pragma unroll
            for (int ht = 0; ht < 4; ++ht) {
                f32x4 b4 = *(const f32x4*)(bv + hc * 64 + ht * 16 + quad * 4);
                #pragma unroll
                for (int r = 0; r < 4; ++r)
                    pv[(size_t)(((b * 32 + c) * 32 + hc * 8 + ht * 2 + s2) * 64
                                + qv * 16 + quad * 4 + r) * 8 + jj]
                        = f2h(acc[ht][r] + b4[r]);
            }
        }
    }
}

// ---------------------------------------------------------------------------
// Kernel 2: flash attention, key-split partials (round 9 structure) with an
// LDS-ONLY chunk barrier: prefetches (K c+1, mask c+1) now RIDE THROUGH the
// barrier instead of being drained by __syncthreads' vmcnt(0). K prefetch is
// issued first in the chunk body (longest runway). 1024 blocks (8b x 64
// strip x 2 key-half), 4 waves; fixed-max softmax keeps partials additive.
// ---------------------------------------------------------------------------
__global__ __launch_bounds__(256, 2) void attn_kernel(
    const unsigned short* __restrict__ pq, const unsigned short* __restrict__ pk,
    const unsigned short* __restrict__ pv, const int* __restrict__ mask,
    unsigned short* __restrict__ Opart, float* __restrict__ lpart)
{
    __shared__ unsigned short P[2][32][68];       // [buf][q(2 strips)][k], pitch 68
    __shared__ float lsum[4][32];

    const int tid  = threadIdx.x;
    const int wave = tid >> 6;
    const int lane = tid & 63;
    const int col  = lane & 15;
    const int quad = lane >> 4;

    const int b     = blockIdx.x & 7;             // batch == XCD (L2 locality)
    const int strip = (blockIdx.x >> 3) & 63;     // 0..63 (32 rows each)
    const int kh    = blockIdx.x >> 9;            // key half: 0 or 1
    const int q0    = strip << 5;

    // Q B-fragments for both 16-row strips: 16 coalesced 1KB loads, resident.
    f16x8 qf[2][8];
    #pragma unroll
    for (int st = 0; st < 2; ++st) {
        const unsigned short* qb = pq + (size_t)(b * 128 + strip * 2 + st) * 4096
                                      + lane * 8;
        #pragma unroll
        for (int s = 0; s < 8; ++s) qf[st][s] = *(const f16x8*)(qb + s * 512);
    }

    f32x4 O[2][4];                                // [strip][ht] 64-h slice
    #pragma unroll
    for (int st = 0; st < 2; ++st)
        #pragma unroll
        for (int ht = 0; ht < 4; ++ht) O[st][ht] = (f32x4)(0.0f);
    float l0 = 0.0f, l1 = 0.0f;

    const unsigned short* pkb = pk + (size_t)(b * 128) * 4096 + lane * 8;
    const unsigned short* pvb = pv + (size_t)(b * 32) * 32 * 512
                                   + (size_t)wave * 8 * 512 + lane * 8;
    const int* mb0 = mask + (size_t)(b * S_ + q0 + col) * S_ + kh * 1024
                   + wave * 16 + quad * 4;
    const int* mb1 = mb0 + 16 * S_;

    // K double buffer: prologue load for chunk 0 (key tile kh*64 + wave)
    f16x8 kf[2][8];
    #pragma unroll
    for (int s = 0; s < 8; ++s)
        kf[0][s] = *(const f16x8*)(pkb + (size_t)(kh * 64 + wave) * 4096 + s * 512);

    int4 mc0 = nt_load_int4(mb0);
    int4 mc1 = nt_load_int4(mb1);

    #pragma unroll 2
    for (int c = 0; c < 16; ++c) {
        const int pb = c & 1;
        const int cn = (c < 15) ? c + 1 : c;      // clamped prefetch index
        const int gc = kh * 16 + c;               // global 64-key chunk

        // ---- K prefetch for next chunk FIRST (longest runway; rides
        //      through the LDS-only barrier) ----
        {
            const unsigned short* kb = pkb + (size_t)(kh * 64 + cn * 4 + wave) * 4096;
            #pragma unroll
            for (int s = 0; s < 8; ++s)
                kf[pb ^ 1][s] = *(const f16x8*)(kb + s * 512);
        }

        // ---- V loads for this chunk (used after the barrier) ----
        const unsigned short* vb = pvb + (size_t)gc * 32 * 512;
        f16x8 vf[4][2];
        #pragma unroll
        for (int ht = 0; ht < 4; ++ht)
            #pragma unroll
            for (int s2 = 0; s2 < 2; ++s2)
                vf[ht][s2] = *(const f16x8*)(vb + (size_t)(ht * 2 + s2) * 512);

        // ---- mask prefetch for next chunk (non-temporal) ----
        int4 mn0 = nt_load_int4(mb0 + cn * 64);
        int4 mn1 = nt_load_int4(mb1 + cn * 64);

        // ---- S^T = K·Q^T for both strips (key tile kh*64 + c*4 + wave) ----
        f32x4 St0 = (f32x4)(0.0f), St1 = (f32x4)(0.0f);
        #pragma unroll
        for (int s = 0; s < 8; ++s) {
            St0 = __builtin_amdgcn_mfma_f32_16x16x32_f16(kf[pb][s], qf[0][s], St0, 0, 0, 0);
            St1 = __builtin_amdgcn_mfma_f32_16x16x32_f16(kf[pb][s], qf[1][s], St1, 0, 0, 0);
        }

        // ---- fixed-max softmax: p = exp(s/16 - 6), masked -> 0 ----
        {
            int mi[4] = { mc0.x, mc0.y, mc0.z, mc0.w };
            unsigned long long pk64 = 0;
            #pragma unroll
            for (int r = 0; r < 4; ++r) {
                float p = (mi[r] == 0) ? 0.0f : __expf(St0[r] * 0.0625f - 6.0f);
                _Float16 ph = (_Float16)p;
                l0 += (float)ph;                  // denom from quantized p
                pk64 |= (unsigned long long)__builtin_bit_cast(unsigned short, ph)
                        << (16 * r);
            }
            *(unsigned long long*)&P[pb][col][wave * 16 + quad * 4] = pk64;
        }
        {
            int mi[4] = { mc1.x, mc1.y, mc1.z, mc1.w };
            unsigned long long pk64 = 0;
            #pragma unroll
            for (int r = 0; r < 4; ++r) {
                float p = (mi[r] == 0) ? 0.0f : __expf(St1[r] * 0.0625f - 6.0f);
                _Float16 ph = (_Float16)p;
                l1 += (float)ph;
                pk64 |= (unsigned long long)__builtin_bit_cast(unsigned short, ph)
                        << (16 * r);
            }
            *(unsigned long long*)&P[pb][16 + col][wave * 16 + quad * 4] = pk64;
        }
        mc0 = mn0; mc1 = mn1;

        lds_barrier();                            // P visible; NO vmem drain

        // ---- O += P · V (64-key chunk, this wave's 64-h slice, 2 strips) ----
        #pragma unroll
        for (int st = 0; st < 2; ++st) {
            #pragma unroll
            for (int s2 = 0; s2 < 2; ++s2) {
                union { unsigned long long u[2]; f16x8 v; } pu;
                const unsigned short* pr = &P[pb][st * 16 + col][s2 * 32 + quad * 8];
                pu.u[0] = *(const unsigned long long*)pr;
                pu.u[1] = *(const unsigned long long*)(pr + 4);
                f16x8 pf = pu.v;
                #pragma unroll
                for (int ht = 0; ht < 4; ++ht)
                    O[st][ht] = __builtin_amdgcn_mfma_f32_16x16x32_f16(pf, vf[ht][s2], O[st][ht], 0, 0, 0);
            }
        }
    }

    // ---- reduce l per strip: quads via shfl, waves via LDS ----
    l0 += __shfl_xor(l0, 16); l0 += __shfl_xor(l0, 32);
    l1 += __shfl_xor(l1, 16); l1 += __shfl_xor(l1, 32);
    if (lane < 16) { lsum[wave][lane] = l0; lsum[wave][16 + lane] = l1; }
    __syncthreads();

    if (wave == 0 && lane < 16) {
        #pragma unroll
        for (int st = 0; st < 2; ++st) {
            float lt = lsum[0][st * 16 + lane] + lsum[1][st * 16 + lane]
                     + lsum[2][st * 16 + lane] + lsum[3][st * 16 + lane];
            lpart[(size_t)kh * NROW + b * S_ + q0 + st * 16 + lane] = lt;
        }
    }

    // ---- store fp16 partial O straight from registers ----
    unsigned short* ob = Opart + (size_t)kh * NROW * H_ + (size_t)(b * S_) * H_;
    #pragma unroll
    for (int st = 0; st < 2; ++st)
        #pragma unroll
        for (int ht = 0; ht < 4; ++ht)
            #pragma unroll
            for (int r = 0; r < 4; ++r)
                ob[(size_t)(q0 + st * 16 + quad * 4 + r) * H_
                   + wave * 64 + ht * 16 + col] = f2h(O[st][ht][r]);
}

// ---------------------------------------------------------------------------
// Kernel 3: merge the 2 key-half partials + normalize + LayerNorm.
// ---------------------------------------------------------------------------
__global__ __launch_bounds__(256) void merge_ln_kernel(
    const unsigned short* __restrict__ Opart, const float* __restrict__ lpart,
    const float* __restrict__ gamma, const float* __restrict__ beta,
    float* __restrict__ out)
{
    const int R0 = blockIdx.x * 16;
    const int q  = threadIdx.x >> 4;              // row R0+q
    const int i  = threadIdx.x & 15;

    const size_t row = (size_t)(R0 + q);
    float linv = 1.0f / (lpart[row] + lpart[NROW + row]);

    const unsigned short* o0 = Opart + row * H_;
    const unsigned short* o1 = o0 + (size_t)NROW * H_;

    float vals[16];
    float sum = 0.0f;
    #pragma unroll
    for (int j = 0; j < 16; ++j) {
        int h = j * 16 + i;
        vals[j] = (h2f(o0[h]) + h2f(o1[h])) * linv;
        sum += vals[j];
    }
    sum += __shfl_xor(sum, 1);
    sum += __shfl_xor(sum, 2);
    sum += __shfl_xor(sum, 4);
    sum += __shfl_xor(sum, 8);
    float mu = sum * (1.0f / H_);
    float sq = 0.0f;
    #pragma unroll
    for (int j = 0; j < 16; ++j) {
        float d = vals[j] - mu;
        sq += d * d;
    }
    sq += __shfl_xor(sq, 1);
    sq += __shfl_xor(sq, 2);
    sq += __shfl_xor(sq, 4);
    sq += __shfl_xor(sq, 8);
    float rstd = rsqrtf(sq * (1.0f / H_) + 1e-6f);

    float* orow = out + row * H_;
    #pragma unroll
    for (int j = 0; j < 16; ++j) {
        int h = j * 16 + i;
        orow[h] = (vals[j] - mu) * rstd * gamma[h] + beta[h];
    }
}

// ---------------------------------------------------------------------------
extern "C" void kernel_launch(void* const* d_in, const int* in_sizes, int n_in,
                              void* d_out, int out_size, void* d_ws, size_t ws_size,
                              hipStream_t stream)
{
    const float* query = (const float*)d_in[0];
    const float* key   = (const float*)d_in[1];
    const float* value = (const float*)d_in[2];
    const int*   mask  = (const int*)d_in[3];
    const float* Wq = (const float*)d_in[4];
    const float* bq = (const float*)d_in[5];
    const float* Wk = (const float*)d_in[6];
    const float* bk = (const float*)d_in[7];
    const float* Wv = (const float*)d_in[8];
    const float* bv = (const float*)d_in[9];
    const float* gamma = (const float*)d_in[10];
    const float* beta  = (const float*)d_in[11];
    float* out = (float*)d_out;

    const size_t NQK = (size_t)B_ * S_ * H_;             // 4.19M elem each
    unsigned short* pq = (unsigned short*)d_ws;          // frag-packed Q (fp16)
    unsigned short* pk = pq + NQK;                       // frag-packed K (fp16)
    unsigned short* pv = pk + NQK;                       // frag-packed V (fp16)
    unsigned short* wt = pv + NQK;                       // [3][256][96] fp16
    unsigned short* Op = wt + (size_t)3 * H_ * IN_;      // [2][NROW][256] fp16
    float*          lp = (float*)(Op + (size_t)2 * NROW * H_);  // [2][NROW] fp32

    wconv_kernel<<<24, 256, 0, stream>>>(Wq, Wk, Wv, wt);
    proj_kernel3<<<B_ * S_ / 16, 256, 0, stream>>>(query, key, value, wt,
                                                   bq, bk, bv, pq, pk, pv);
    attn_kernel<<<B_ * S_ / 32 * 2, 256, 0, stream>>>(pq, pk, pv, mask, Op, lp);
    merge_ln_kernel<<<NROW / 16, 256, 0, stream>>>(Op, lp, gamma, beta, out);
}